// Round 13
// baseline (285.552 us; speedup 1.0000x reference)
//
#include <hip/hip_runtime.h>
#include <hip/hip_bf16.h>

#define DIM 256
#define NHEADS 4
#define HDIM 64
#define NPIX 2304          // 48*48
#define NBATCH 8
#define SCALE_L2E 0.18033688011112042f   // 0.125 * log2(e), folded into Q
#define CLAMP_L2E 8.656170245332781f     // 6.0  * log2(e)

typedef __hip_bfloat16 bf16;
typedef __bf16 bf16x8 __attribute__((ext_vector_type(8)));
typedef float  f32x4  __attribute__((ext_vector_type(4)));
typedef float  f32x16 __attribute__((ext_vector_type(16)));

__device__ __forceinline__ unsigned int pack2bf(float a, float b) {
    __hip_bfloat162 h = __float22bfloat162_rn(float2{a, b});
    union { __hip_bfloat162 h; unsigned int u; } c; c.h = h;
    return c.u;
}

// ---- 4 weight matrices (256x256 f32, row-major (m,c)) -> bf16, concatenated.
__global__ __launch_bounds__(256) void cvt_w_kernel(
    const float* __restrict__ w0, const float* __restrict__ w1,
    const float* __restrict__ w2, const float* __restrict__ w3,
    bf16* __restrict__ out)
{
    const int sel = blockIdx.y;
    const float* src = sel == 0 ? w0 : sel == 1 ? w1 : sel == 2 ? w2 : w3;
    const int i = (blockIdx.x * 256 + threadIdx.x) * 8;
    float4 a = *(const float4*)(src + i);
    float4 b = *(const float4*)(src + i + 4);
    uint4 u;
    u.x = pack2bf(a.x, a.y); u.y = pack2bf(a.z, a.w);
    u.z = pack2bf(b.x, b.y); u.w = pack2bf(b.z, b.w);
    *(uint4*)(void*)(out + (size_t)sel * 65536 + i) = u;
}

// ---- src/tgt (b,c,n) f32 -> (b,n,c) bf16 via LDS tile transpose.
__global__ __launch_bounds__(256) void txp_kernel(
    const float* __restrict__ src, const float* __restrict__ tgt,
    bf16* __restrict__ oS, bf16* __restrict__ oT)
{
    const int b = blockIdx.z & 7;
    const float* in = (blockIdx.z >> 3) ? tgt : src;
    bf16* out = (blockIdx.z >> 3) ? oT : oS;
    const int n0 = blockIdx.x * 64, c0 = blockIdx.y * 64;
    __shared__ float tile[64][65];
    const int t = threadIdx.x;
#pragma unroll
    for (int i = 0; i < 4; ++i) {
        int idx = t + i * 256;
        int cl = idx >> 4, n4 = (idx & 15) * 4;
        float4 v = *(const float4*)(in + ((size_t)b * DIM + c0 + cl) * NPIX + n0 + n4);
        tile[cl][n4] = v.x; tile[cl][n4 + 1] = v.y;
        tile[cl][n4 + 2] = v.z; tile[cl][n4 + 3] = v.w;
    }
    __syncthreads();
#pragma unroll
    for (int i = 0; i < 2; ++i) {
        int idx = t + i * 256;
        int nl = idx >> 3, c8 = (idx & 7) * 8;
        uint4 u;
        u.x = pack2bf(tile[c8 + 0][nl], tile[c8 + 1][nl]);
        u.y = pack2bf(tile[c8 + 2][nl], tile[c8 + 3][nl]);
        u.z = pack2bf(tile[c8 + 4][nl], tile[c8 + 5][nl]);
        u.w = pack2bf(tile[c8 + 6][nl], tile[c8 + 7][nl]);
        *(uint4*)(void*)(out + ((size_t)b * NPIX + n0 + nl) * DIM + c0 + c8) = u;
    }
}

// ---- 1x1 conv as MFMA GEMM with register double-buffered K-prefetch.
// D[n][m] = sum_c X[n][c] * W[m][c] + bias[m].
// X: (b,n,c) bf16; W: (m,c) bf16. Block: 64 n x 128 m, 4 waves (16 n each).
// MODE 0: f32 (b,c,n) -> Yf. MODE 1: bf16 (b,h,n,d)*scale -> Yb (Q,K).
// MODE 2: bf16 (b,c,n) -> Yb (V).
template <int MODE>
__global__ __launch_bounds__(256) void conv_kernel(
    const bf16* __restrict__ X, const bf16* __restrict__ Wb,
    const float* __restrict__ bias, float scale,
    bf16* __restrict__ Yb, float* __restrict__ Yf)
{
    const int b  = blockIdx.z, mh = blockIdx.y;
    const int n0 = blockIdx.x * 64;
    const int w  = threadIdx.x >> 6, l = threadIdx.x & 63;
    const int lo = l & 15, hi = l >> 4;
    const int nrow = n0 + w * 16 + lo;

    const bf16* xp = X + ((size_t)b * NPIX + nrow) * DIM + hi * 8;
    const bf16* wp = Wb + ((size_t)(mh * 128 + lo)) * DIM + hi * 8;

    f32x4 acc[8];
#pragma unroll
    for (int mt = 0; mt < 8; ++mt) acc[mt] = (f32x4){0.f, 0.f, 0.f, 0.f};

    // preload k0 = 0 fragments
    bf16x8 a = *(const bf16x8*)(const void*)(xp);
    bf16x8 bfr[8];
#pragma unroll
    for (int mt = 0; mt < 8; ++mt)
        bfr[mt] = *(const bf16x8*)(const void*)(wp + (size_t)mt * 16 * DIM);

#pragma unroll
    for (int k0 = 0; k0 < DIM; k0 += 32) {
        bf16x8 a2, bfr2[8];
        const int kn = (k0 + 32) & (DIM - 1);   // wrap: last-iter loads are L1 hits
        a2 = *(const bf16x8*)(const void*)(xp + kn);
#pragma unroll
        for (int mt = 0; mt < 8; ++mt)
            bfr2[mt] = *(const bf16x8*)(const void*)(wp + (size_t)mt * 16 * DIM + kn);
#pragma unroll
        for (int mt = 0; mt < 8; ++mt)
            acc[mt] = __builtin_amdgcn_mfma_f32_16x16x32_bf16(a, bfr[mt], acc[mt], 0, 0, 0);
        a = a2;
#pragma unroll
        for (int mt = 0; mt < 8; ++mt) bfr[mt] = bfr2[mt];
    }

    const int nb = n0 + w * 16 + hi * 4;   // first of 4 consecutive n (rows r)
#pragma unroll
    for (int mt = 0; mt < 8; ++mt) {
        const int m = mh * 128 + mt * 16 + lo;
        const float bv = bias[m];
        if (MODE == 1) {
            const int h = m >> 6, d = m & 63;
            bf16* p = Yb + (((size_t)b * NHEADS + h) * NPIX + nb) * HDIM + d;
#pragma unroll
            for (int r = 0; r < 4; ++r)
                p[(size_t)r * HDIM] = __float2bfloat16((acc[mt][r] + bv) * scale);
        } else if (MODE == 2) {
            bf16* p = Yb + ((size_t)b * DIM + m) * NPIX + nb;
            *(unsigned int*)(void*)(p)     = pack2bf(acc[mt][0] + bv, acc[mt][1] + bv);
            *(unsigned int*)(void*)(p + 2) = pack2bf(acc[mt][2] + bv, acc[mt][3] + bv);
        } else {
            float4 v = make_float4(acc[mt][0] + bv, acc[mt][1] + bv,
                                   acc[mt][2] + bv, acc[mt][3] + bv);
            *(float4*)(void*)(Yf + ((size_t)b * DIM + m) * NPIX + nb) = v;
        }
    }
}

// ---- MFMA flash attention, 32x32x16, no LDS, permlane-only cross-lane,
// register double-buffered K/V prefetch, 32 queries per wave (occupancy 2x).
// Q,K: (b,h,n,d) bf16 (Q prescaled). V: (b,c,n) bf16. Op: (b,n,c) bf16.
// Block: 1 wave = 32 queries. Grid: (72, 4, 8) = 2304 waves.
// QK^T swapped: S^T = mfma(K, Q) => lane(ln,h2) reg r holds
// S[key = k0 + (r&3)+8*(r>>2)+4*h2][q = nq + ln].
// PV B-frag (P^T) built with 4 v_permlane32_swap_b32 per 32 keys.
__global__ __launch_bounds__(64) void attn_kernel(
    const bf16* __restrict__ Qt, const bf16* __restrict__ Kt,
    const bf16* __restrict__ Vt, bf16* __restrict__ Op)
{
    const int b = blockIdx.z, h = blockIdx.y;
    const int l = threadIdx.x & 63;
    const int ln = l & 31, h2 = l >> 5;
    const int nq = blockIdx.x * 32;

    const size_t qkb = ((size_t)b * NHEADS + h) * (size_t)NPIX * HDIM;
    const bf16* Qb = Qt + qkb;
    const bf16* Kb = Kt + qkb;
    const bf16* Vb = Vt + ((size_t)b * DIM + h * HDIM) * (size_t)NPIX;

    // Q B-frags (held in regs): B[d_loc=h2*8+j][q=ln] for d-chunk dk
    bf16x8 qf[4];
#pragma unroll
    for (int dk = 0; dk < 4; ++dk)
        qf[dk] = *(const bf16x8*)(const void*)(
            Qb + (size_t)(nq + ln) * HDIM + dk * 16 + h2 * 8);

    f32x16 oacc[2];   // [dt]: O^T[d = dt*32 + row][q]
#pragma unroll
    for (int dt = 0; dt < 2; ++dt)
#pragma unroll
        for (int r = 0; r < 16; ++r) oacc[dt][r] = 0.f;
    float lsum = 0.f;

    // ---- preload iter-0 K/V fragments
    bf16x8 kf[4];        // A[key=ln][d_loc=h2*8+j], d-chunk dk
    bf16x8 vf[2][2];     // A[d=dt*32+ln][k_loc=h2*8+j], key-half kb
#pragma unroll
    for (int dk = 0; dk < 4; ++dk)
        kf[dk] = *(const bf16x8*)(const void*)(
            Kb + (size_t)ln * HDIM + dk * 16 + h2 * 8);
#pragma unroll
    for (int kb = 0; kb < 2; ++kb)
#pragma unroll
        for (int dt = 0; dt < 2; ++dt)
            vf[kb][dt] = *(const bf16x8*)(const void*)(
                Vb + (size_t)(dt * 32 + ln) * NPIX + kb * 16 + h2 * 8);

    for (int k0 = 0; k0 < NPIX; k0 += 32) {
        // ---- issue next iteration's loads first (wrap keeps addresses valid)
        const int kn = (k0 + 32) % NPIX;
        bf16x8 kf2[4];
        bf16x8 vf2[2][2];
#pragma unroll
        for (int dk = 0; dk < 4; ++dk)
            kf2[dk] = *(const bf16x8*)(const void*)(
                Kb + (size_t)(kn + ln) * HDIM + dk * 16 + h2 * 8);
#pragma unroll
        for (int kb = 0; kb < 2; ++kb)
#pragma unroll
            for (int dt = 0; dt < 2; ++dt)
                vf2[kb][dt] = *(const bf16x8*)(const void*)(
                    Vb + (size_t)(dt * 32 + ln) * NPIX + kn + kb * 16 + h2 * 8);

        // ---- compute on current buffers
        f32x16 s;
#pragma unroll
        for (int r = 0; r < 16; ++r) s[r] = 0.f;
#pragma unroll
        for (int dk = 0; dk < 4; ++dk)
            s = __builtin_amdgcn_mfma_f32_32x32x16_bf16(kf[dk], qf[dk], s, 0, 0, 0);

        // P = exp2(clamp(S)); word p covers keys 8*(p>>1)+4*h2+2*(p&1)+{0,1}
        float ls = 0.f;
        unsigned int pk[8];
#pragma unroll
        for (int p = 0; p < 8; ++p) {
            float ea = __builtin_amdgcn_exp2f(
                __builtin_amdgcn_fmed3f(s[2 * p],     -CLAMP_L2E, CLAMP_L2E));
            float eb = __builtin_amdgcn_exp2f(
                __builtin_amdgcn_fmed3f(s[2 * p + 1], -CLAMP_L2E, CLAMP_L2E));
            ls += ea + eb;
            pk[p] = pack2bf(ea, eb);
        }
        lsum += ls;

        // P^T B-frags via half-wave swaps:
        // after swap(a,b): a = {a.lo32 | b.lo32}, b = {a.hi32 | b.hi32}
        unsigned int c00 = pk[0], c02 = pk[2], c01 = pk[1], c03 = pk[3];
        unsigned int c10 = pk[4], c12 = pk[6], c11 = pk[5], c13 = pk[7];
        asm("v_permlane32_swap_b32 %0, %1" : "+v"(c00), "+v"(c02));
        asm("v_permlane32_swap_b32 %0, %1" : "+v"(c01), "+v"(c03));
        asm("v_permlane32_swap_b32 %0, %1" : "+v"(c10), "+v"(c12));
        asm("v_permlane32_swap_b32 %0, %1" : "+v"(c11), "+v"(c13));
        union { unsigned int u[4]; bf16x8 v; } pb0, pb1;
        pb0.u[0] = c00; pb0.u[1] = c01; pb0.u[2] = c02; pb0.u[3] = c03;
        pb1.u[0] = c10; pb1.u[1] = c11; pb1.u[2] = c12; pb1.u[3] = c13;

#pragma unroll
        for (int dt = 0; dt < 2; ++dt) {
            oacc[dt] = __builtin_amdgcn_mfma_f32_32x32x16_bf16(vf[0][dt], pb0.v, oacc[dt], 0, 0, 0);
            oacc[dt] = __builtin_amdgcn_mfma_f32_32x32x16_bf16(vf[1][dt], pb1.v, oacc[dt], 0, 0, 0);
        }

        // ---- rotate prefetch buffers
#pragma unroll
        for (int dk = 0; dk < 4; ++dk) kf[dk] = kf2[dk];
#pragma unroll
        for (int kb = 0; kb < 2; ++kb)
#pragma unroll
            for (int dt = 0; dt < 2; ++dt) vf[kb][dt] = vf2[kb][dt];
    }

    // normalize: lane's 32 outputs all belong to query q = nq + ln
    float t = lsum + __shfl_xor(lsum, 32);
    const float inv = 1.f / t;

    // store Op (b,n,c): n = nq + ln; c = h*64 + dt*32 + 8*g + 4*h2 + (0..3)
    bf16* rowp = Op + ((size_t)b * NPIX + nq + ln) * DIM + h * HDIM;
#pragma unroll
    for (int dt = 0; dt < 2; ++dt)
#pragma unroll
        for (int g = 0; g < 4; ++g) {
            float v0 = oacc[dt][g * 4 + 0] * inv;
            float v1 = oacc[dt][g * 4 + 1] * inv;
            float v2 = oacc[dt][g * 4 + 2] * inv;
            float v3 = oacc[dt][g * 4 + 3] * inv;
            uint2 u = make_uint2(pack2bf(v0, v1), pack2bf(v2, v3));
            *(uint2*)(void*)(rowp + dt * 32 + g * 8 + h2 * 4) = u;
        }
}

extern "C" void kernel_launch(void* const* d_in, const int* in_sizes, int n_in,
                              void* d_out, int out_size, void* d_ws, size_t ws_size,
                              hipStream_t stream) {
    const float* src = (const float*)d_in[0];
    const float* tgt = (const float*)d_in[1];
    const float* qw  = (const float*)d_in[2];
    const float* qb  = (const float*)d_in[3];
    const float* kw  = (const float*)d_in[4];
    const float* kb  = (const float*)d_in[5];
    const float* vw  = (const float*)d_in[6];
    const float* vb  = (const float*)d_in[7];
    const float* ow  = (const float*)d_in[8];
    const float* ob  = (const float*)d_in[9];
    float* out = (float*)d_out;

    const size_t TEN = (size_t)NBATCH * DIM * NPIX;  // 4,718,592
    bf16* Wbf  = (bf16*)d_ws;          // 4 x 65536
    bf16* XbfS = Wbf  + 4 * 65536;     // (b,n,c)
    bf16* XbfT = XbfS + TEN;           // (b,n,c)
    bf16* Qt   = XbfT + TEN;           // (b,h,n,d), prescaled
    bf16* Kt   = Qt   + TEN;           // (b,h,n,d)
    bf16* Vt   = Kt   + TEN;           // (b,c,n)
    bf16* Op   = Vt   + TEN;           // (b,n,c)

    cvt_w_kernel<<<dim3(32, 4, 1), 256, 0, stream>>>(qw, kw, vw, ow, Wbf);
    txp_kernel<<<dim3(NPIX / 64, DIM / 64, 2 * NBATCH), 256, 0, stream>>>(src, tgt, XbfS, XbfT);

    dim3 cgrid(NPIX / 64, 2, NBATCH);
    conv_kernel<1><<<cgrid, 256, 0, stream>>>(XbfS, Wbf,             qb, SCALE_L2E, Qt, nullptr);
    conv_kernel<1><<<cgrid, 256, 0, stream>>>(XbfT, Wbf + 1 * 65536, kb, 1.0f,      Kt, nullptr);
    conv_kernel<2><<<cgrid, 256, 0, stream>>>(XbfT, Wbf + 2 * 65536, vb, 1.0f,      Vt, nullptr);

    attn_kernel<<<dim3(NPIX / 32, NHEADS, NBATCH), 64, 0, stream>>>(Qt, Kt, Vt, Op);

    conv_kernel<0><<<cgrid, 256, 0, stream>>>(Op, Wbf + 3 * 65536, ob, 1.0f, nullptr, out);
}

// Round 14
// 234.616 us; speedup vs baseline: 1.2171x; 1.2171x over previous
//
#include <hip/hip_runtime.h>
#include <hip/hip_bf16.h>

#define DIM 256
#define NHEADS 4
#define HDIM 64
#define NPIX 2304          // 48*48
#define NBATCH 8
#define KCN 72             // NPIX/32 key chunks
#define SCALE_L2E 0.18033688011112042f   // 0.125 * log2(e), folded into Q
#define CLAMP_L2E 8.656170245332781f     // 6.0  * log2(e)

typedef __hip_bfloat16 bf16;
typedef __bf16 bf16x8 __attribute__((ext_vector_type(8)));
typedef float  f32x4  __attribute__((ext_vector_type(4)));
typedef float  f32x16 __attribute__((ext_vector_type(16)));

__device__ __forceinline__ unsigned int pack2bf(float a, float b) {
    __hip_bfloat162 h = __float22bfloat162_rn(float2{a, b});
    union { __hip_bfloat162 h; unsigned int u; } c; c.h = h;
    return c.u;
}

// ---- 4 weight matrices (256x256 f32, row-major (m,c)) -> bf16, concatenated.
__global__ __launch_bounds__(256) void cvt_w_kernel(
    const float* __restrict__ w0, const float* __restrict__ w1,
    const float* __restrict__ w2, const float* __restrict__ w3,
    bf16* __restrict__ out)
{
    const int sel = blockIdx.y;
    const float* src = sel == 0 ? w0 : sel == 1 ? w1 : sel == 2 ? w2 : w3;
    const int i = (blockIdx.x * 256 + threadIdx.x) * 8;
    float4 a = *(const float4*)(src + i);
    float4 b = *(const float4*)(src + i + 4);
    uint4 u;
    u.x = pack2bf(a.x, a.y); u.y = pack2bf(a.z, a.w);
    u.z = pack2bf(b.x, b.y); u.w = pack2bf(b.z, b.w);
    *(uint4*)(void*)(out + (size_t)sel * 65536 + i) = u;
}

// ---- src/tgt (b,c,n) f32 -> (b,n,c) bf16 via LDS tile transpose.
__global__ __launch_bounds__(256) void txp_kernel(
    const float* __restrict__ src, const float* __restrict__ tgt,
    bf16* __restrict__ oS, bf16* __restrict__ oT)
{
    const int b = blockIdx.z & 7;
    const float* in = (blockIdx.z >> 3) ? tgt : src;
    bf16* out = (blockIdx.z >> 3) ? oT : oS;
    const int n0 = blockIdx.x * 64, c0 = blockIdx.y * 64;
    __shared__ float tile[64][65];
    const int t = threadIdx.x;
#pragma unroll
    for (int i = 0; i < 4; ++i) {
        int idx = t + i * 256;
        int cl = idx >> 4, n4 = (idx & 15) * 4;
        float4 v = *(const float4*)(in + ((size_t)b * DIM + c0 + cl) * NPIX + n0 + n4);
        tile[cl][n4] = v.x; tile[cl][n4 + 1] = v.y;
        tile[cl][n4 + 2] = v.z; tile[cl][n4 + 3] = v.w;
    }
    __syncthreads();
#pragma unroll
    for (int i = 0; i < 2; ++i) {
        int idx = t + i * 256;
        int nl = idx >> 3, c8 = (idx & 7) * 8;
        uint4 u;
        u.x = pack2bf(tile[c8 + 0][nl], tile[c8 + 1][nl]);
        u.y = pack2bf(tile[c8 + 2][nl], tile[c8 + 3][nl]);
        u.z = pack2bf(tile[c8 + 4][nl], tile[c8 + 5][nl]);
        u.w = pack2bf(tile[c8 + 6][nl], tile[c8 + 7][nl]);
        *(uint4*)(void*)(out + ((size_t)b * NPIX + n0 + nl) * DIM + c0 + c8) = u;
    }
}

// ---- 1x1 conv as MFMA GEMM with register double-buffered K-prefetch.
// D[n][m] = sum_c X[n][c] * W[m][c] + bias[m].
// X: (b,n,c) bf16; W: (m,c) bf16. Block: 64 n x 128 m, 4 waves (16 n each).
// MODE 0: f32 (b,c,n) -> Yf.
// MODE 1: bf16 *scale -> fragment-order QF/KF: [bh][kc][dk][lane][j]
//         (lane = h2_d*32 + (n&31), j = d&7; see attn_kernel).
// MODE 2: bf16 -> fragment-order VF: [bh][kc][kb][dt][lane][j]
//         (lane = h2_n*32 + (dv&31), j = n&7).
template <int MODE>
__global__ __launch_bounds__(256) void conv_kernel(
    const bf16* __restrict__ X, const bf16* __restrict__ Wb,
    const float* __restrict__ bias, float scale,
    bf16* __restrict__ Yb, float* __restrict__ Yf)
{
    const int b  = blockIdx.z, mh = blockIdx.y;
    const int n0 = blockIdx.x * 64;
    const int w  = threadIdx.x >> 6, l = threadIdx.x & 63;
    const int lo = l & 15, hi = l >> 4;
    const int nrow = n0 + w * 16 + lo;

    const bf16* xp = X + ((size_t)b * NPIX + nrow) * DIM + hi * 8;
    const bf16* wp = Wb + ((size_t)(mh * 128 + lo)) * DIM + hi * 8;

    f32x4 acc[8];
#pragma unroll
    for (int mt = 0; mt < 8; ++mt) acc[mt] = (f32x4){0.f, 0.f, 0.f, 0.f};

    // preload k0 = 0 fragments
    bf16x8 a = *(const bf16x8*)(const void*)(xp);
    bf16x8 bfr[8];
#pragma unroll
    for (int mt = 0; mt < 8; ++mt)
        bfr[mt] = *(const bf16x8*)(const void*)(wp + (size_t)mt * 16 * DIM);

#pragma unroll
    for (int k0 = 0; k0 < DIM; k0 += 32) {
        bf16x8 a2, bfr2[8];
        const int kn = (k0 + 32) & (DIM - 1);   // wrap: last-iter loads are L1 hits
        a2 = *(const bf16x8*)(const void*)(xp + kn);
#pragma unroll
        for (int mt = 0; mt < 8; ++mt)
            bfr2[mt] = *(const bf16x8*)(const void*)(wp + (size_t)mt * 16 * DIM + kn);
#pragma unroll
        for (int mt = 0; mt < 8; ++mt)
            acc[mt] = __builtin_amdgcn_mfma_f32_16x16x32_bf16(a, bfr[mt], acc[mt], 0, 0, 0);
        a = a2;
#pragma unroll
        for (int mt = 0; mt < 8; ++mt) bfr[mt] = bfr2[mt];
    }

    const int nb = n0 + w * 16 + hi * 4;   // first of 4 consecutive n (rows r)
#pragma unroll
    for (int mt = 0; mt < 8; ++mt) {
        const int m = mh * 128 + mt * 16 + lo;
        const float bv = bias[m];
        if (MODE == 1) {
            const int h = m >> 6, d = m & 63;
            const size_t fb = (((size_t)(b * NHEADS + h) * KCN + (nb >> 5)) * 4 + (d >> 4)) * 512
                            + ((((d >> 3) & 1) * 32) + (nb & 31)) * 8 + (d & 7);
#pragma unroll
            for (int r = 0; r < 4; ++r)
                Yb[fb + r * 8] = __float2bfloat16((acc[mt][r] + bv) * scale);
        } else if (MODE == 2) {
            const int h = m >> 6, dv = m & 63;
            const size_t fb = ((((size_t)(b * NHEADS + h) * KCN + (nb >> 5)) * 2 + ((nb >> 4) & 1)) * 2
                               + (dv >> 5)) * 512
                            + ((((nb >> 3) & 1) * 32) + (dv & 31)) * 8 + (nb & 7);
            uint2 u = make_uint2(pack2bf(acc[mt][0] + bv, acc[mt][1] + bv),
                                 pack2bf(acc[mt][2] + bv, acc[mt][3] + bv));
            *(uint2*)(void*)(Yb + fb) = u;
        } else {
            float4 v = make_float4(acc[mt][0] + bv, acc[mt][1] + bv,
                                   acc[mt][2] + bv, acc[mt][3] + bv);
            *(float4*)(void*)(Yf + ((size_t)b * DIM + m) * NPIX + nb) = v;
        }
    }
}

// ---- MFMA flash attention, 32x32x16, no LDS, permlane-only cross-lane,
// register double-buffered K/V prefetch, FRAGMENT-ORDER operands:
// every load is base + lane*16B, perfectly coalesced (8 lines/instr).
// QF/KF: [bh][kc][dk][64 lanes][8]  (2048 elems per kc)
// VF:    [bh][kc][kb][dt][64 lanes][8] (2048 elems per kc)
// Op: (b,n,c) bf16. Block: 1 wave = 64 queries (2 sub-tiles). Grid (36,4,8).
__global__ __launch_bounds__(64) void attn_kernel(
    const bf16* __restrict__ Qt, const bf16* __restrict__ Kt,
    const bf16* __restrict__ Vt, bf16* __restrict__ Op)
{
    const int b = blockIdx.z, h = blockIdx.y;
    const int l = threadIdx.x & 63;
    const int ln = l & 31, h2 = l >> 5;
    const int nq = blockIdx.x * 64;
    const int bh = b * NHEADS + h;

    const bf16* QB = Qt + ((size_t)bh * KCN + blockIdx.x * 2) * 2048 + l * 8;
    const bf16* KB = Kt + (size_t)bh * KCN * 2048 + l * 8;
    const bf16* VB = Vt + (size_t)bh * KCN * 2048 + l * 8;

    // Q B-frags: lane holds Q[q=nq+qs*32+ln][dk*16+h2*8+j]
    bf16x8 qf[2][4];
#pragma unroll
    for (int qs = 0; qs < 2; ++qs)
#pragma unroll
        for (int dk = 0; dk < 4; ++dk)
            qf[qs][dk] = *(const bf16x8*)(const void*)(QB + qs * 2048 + dk * 512);

    f32x16 oacc[2][2];   // [qs][dt]: O^T[d = dt*32 + row][q]
#pragma unroll
    for (int qs = 0; qs < 2; ++qs)
#pragma unroll
        for (int dt = 0; dt < 2; ++dt)
#pragma unroll
            for (int r = 0; r < 16; ++r) oacc[qs][dt][r] = 0.f;
    float lsum[2] = {0.f, 0.f};

    // ---- preload kc=0 fragments
    bf16x8 kf[4];        // A[key=ln][d_loc=h2*8+j]
    bf16x8 vf[2][2];     // A[d=dt*32+ln][k_loc=kb*16+h2*8+j]
#pragma unroll
    for (int dk = 0; dk < 4; ++dk)
        kf[dk] = *(const bf16x8*)(const void*)(KB + dk * 512);
#pragma unroll
    for (int kb = 0; kb < 2; ++kb)
#pragma unroll
        for (int dt = 0; dt < 2; ++dt)
            vf[kb][dt] = *(const bf16x8*)(const void*)(VB + kb * 1024 + dt * 512);

    for (int kc = 0; kc < KCN; ++kc) {
        // ---- issue next chunk's loads first (wrap: last-iter loads are L1 hits)
        const int kcn = (kc + 1) == KCN ? 0 : (kc + 1);
        const bf16* KBn = KB + (size_t)kcn * 2048;
        const bf16* VBn = VB + (size_t)kcn * 2048;
        bf16x8 kf2[4];
        bf16x8 vf2[2][2];
#pragma unroll
        for (int dk = 0; dk < 4; ++dk)
            kf2[dk] = *(const bf16x8*)(const void*)(KBn + dk * 512);
#pragma unroll
        for (int kb = 0; kb < 2; ++kb)
#pragma unroll
            for (int dt = 0; dt < 2; ++dt)
                vf2[kb][dt] = *(const bf16x8*)(const void*)(VBn + kb * 1024 + dt * 512);

        // ---- compute on current buffers
#pragma unroll
        for (int qs = 0; qs < 2; ++qs) {
            f32x16 s;
#pragma unroll
            for (int r = 0; r < 16; ++r) s[r] = 0.f;
#pragma unroll
            for (int dk = 0; dk < 4; ++dk)
                s = __builtin_amdgcn_mfma_f32_32x32x16_bf16(kf[dk], qf[qs][dk], s, 0, 0, 0);

            // P = exp2(clamp(S)); word p covers keys 8*(p>>1)+4*h2+2*(p&1)+{0,1}
            float ls = 0.f;
            unsigned int pk[8];
#pragma unroll
            for (int p = 0; p < 8; ++p) {
                float ea = __builtin_amdgcn_exp2f(
                    __builtin_amdgcn_fmed3f(s[2 * p],     -CLAMP_L2E, CLAMP_L2E));
                float eb = __builtin_amdgcn_exp2f(
                    __builtin_amdgcn_fmed3f(s[2 * p + 1], -CLAMP_L2E, CLAMP_L2E));
                ls += ea + eb;
                pk[p] = pack2bf(ea, eb);
            }
            lsum[qs] += ls;

            // P^T B-frags via half-wave swaps:
            // after swap(a,b): a = {a.lo32 | b.lo32}, b = {a.hi32 | b.hi32}
            unsigned int c00 = pk[0], c02 = pk[2], c01 = pk[1], c03 = pk[3];
            unsigned int c10 = pk[4], c12 = pk[6], c11 = pk[5], c13 = pk[7];
            asm("v_permlane32_swap_b32 %0, %1" : "+v"(c00), "+v"(c02));
            asm("v_permlane32_swap_b32 %0, %1" : "+v"(c01), "+v"(c03));
            asm("v_permlane32_swap_b32 %0, %1" : "+v"(c10), "+v"(c12));
            asm("v_permlane32_swap_b32 %0, %1" : "+v"(c11), "+v"(c13));
            union { unsigned int u[4]; bf16x8 v; } pb0, pb1;
            pb0.u[0] = c00; pb0.u[1] = c01; pb0.u[2] = c02; pb0.u[3] = c03;
            pb1.u[0] = c10; pb1.u[1] = c11; pb1.u[2] = c12; pb1.u[3] = c13;

#pragma unroll
            for (int dt = 0; dt < 2; ++dt) {
                oacc[qs][dt] = __builtin_amdgcn_mfma_f32_32x32x16_bf16(vf[0][dt], pb0.v, oacc[qs][dt], 0, 0, 0);
                oacc[qs][dt] = __builtin_amdgcn_mfma_f32_32x32x16_bf16(vf[1][dt], pb1.v, oacc[qs][dt], 0, 0, 0);
            }
        }

        // ---- rotate prefetch buffers
#pragma unroll
        for (int dk = 0; dk < 4; ++dk) kf[dk] = kf2[dk];
#pragma unroll
        for (int kb = 0; kb < 2; ++kb)
#pragma unroll
            for (int dt = 0; dt < 2; ++dt) vf[kb][dt] = vf2[kb][dt];
    }

    // normalize: lane's 32 outputs all belong to query q = nq + qs*32 + ln
    float inv[2];
#pragma unroll
    for (int qs = 0; qs < 2; ++qs) {
        float t = lsum[qs] + __shfl_xor(lsum[qs], 32);
        inv[qs] = 1.f / t;
    }

    // store Op (b,n,c): n = nq + qs*32 + ln; c = h*64 + dt*32 + 8*g + 4*h2 + (0..3)
#pragma unroll
    for (int qs = 0; qs < 2; ++qs) {
        bf16* rowp = Op + ((size_t)b * NPIX + nq + qs * 32 + ln) * DIM + h * HDIM;
#pragma unroll
        for (int dt = 0; dt < 2; ++dt)
#pragma unroll
            for (int g = 0; g < 4; ++g) {
                float v0 = oacc[qs][dt][g * 4 + 0] * inv[qs];
                float v1 = oacc[qs][dt][g * 4 + 1] * inv[qs];
                float v2 = oacc[qs][dt][g * 4 + 2] * inv[qs];
                float v3 = oacc[qs][dt][g * 4 + 3] * inv[qs];
                uint2 u = make_uint2(pack2bf(v0, v1), pack2bf(v2, v3));
                *(uint2*)(void*)(rowp + dt * 32 + g * 8 + h2 * 4) = u;
            }
    }
}

extern "C" void kernel_launch(void* const* d_in, const int* in_sizes, int n_in,
                              void* d_out, int out_size, void* d_ws, size_t ws_size,
                              hipStream_t stream) {
    const float* src = (const float*)d_in[0];
    const float* tgt = (const float*)d_in[1];
    const float* qw  = (const float*)d_in[2];
    const float* qb  = (const float*)d_in[3];
    const float* kw  = (const float*)d_in[4];
    const float* kb  = (const float*)d_in[5];
    const float* vw  = (const float*)d_in[6];
    const float* vb  = (const float*)d_in[7];
    const float* ow  = (const float*)d_in[8];
    const float* ob  = (const float*)d_in[9];
    float* out = (float*)d_out;

    const size_t TEN = (size_t)NBATCH * DIM * NPIX;  // 4,718,592
    bf16* Wbf  = (bf16*)d_ws;          // 4 x 65536
    bf16* XbfS = Wbf  + 4 * 65536;     // (b,n,c)
    bf16* XbfT = XbfS + TEN;           // (b,n,c)
    bf16* Qt   = XbfT + TEN;           // fragment-order QF, prescaled
    bf16* Kt   = Qt   + TEN;           // fragment-order KF
    bf16* Vt   = Kt   + TEN;           // fragment-order VF
    bf16* Op   = Vt   + TEN;           // (b,n,c)

    cvt_w_kernel<<<dim3(32, 4, 1), 256, 0, stream>>>(qw, kw, vw, ow, Wbf);
    txp_kernel<<<dim3(NPIX / 64, DIM / 64, 2 * NBATCH), 256, 0, stream>>>(src, tgt, XbfS, XbfT);

    dim3 cgrid(NPIX / 64, 2, NBATCH);
    conv_kernel<1><<<cgrid, 256, 0, stream>>>(XbfS, Wbf,             qb, SCALE_L2E, Qt, nullptr);
    conv_kernel<1><<<cgrid, 256, 0, stream>>>(XbfT, Wbf + 1 * 65536, kb, 1.0f,      Kt, nullptr);
    conv_kernel<2><<<cgrid, 256, 0, stream>>>(XbfT, Wbf + 2 * 65536, vb, 1.0f,      Vt, nullptr);

    attn_kernel<<<dim3(NPIX / 64, NHEADS, NBATCH), 64, 0, stream>>>(Qt, Kt, Vt, Op);

    conv_kernel<0><<<cgrid, 256, 0, stream>>>(Op, Wbf + 3 * 65536, ob, 1.0f, nullptr, out);
}

// Round 15
// 217.914 us; speedup vs baseline: 1.3104x; 1.0766x over previous
//
#include <hip/hip_runtime.h>
#include <hip/hip_bf16.h>

#define DIM 256
#define NHEADS 4
#define HDIM 64
#define NPIX 2304          // 48*48
#define NBATCH 8
#define KCN 72             // NPIX/32 key chunks
#define SCALE_L2E 0.18033688011112042f   // 0.125 * log2(e), folded into Q
#define CLAMP_L2E 8.656170245332781f     // 6.0  * log2(e)

typedef __hip_bfloat16 bf16;
typedef __bf16 bf16x8 __attribute__((ext_vector_type(8)));
typedef float  f32x4  __attribute__((ext_vector_type(4)));
typedef float  f32x16 __attribute__((ext_vector_type(16)));

__device__ __forceinline__ unsigned int pack2bf(float a, float b) {
    __hip_bfloat162 h = __float22bfloat162_rn(float2{a, b});
    union { __hip_bfloat162 h; unsigned int u; } c; c.h = h;
    return c.u;
}

// ---- 4 weight matrices (256x256 f32, row-major (m,c)) -> bf16, concatenated.
__global__ __launch_bounds__(256) void cvt_w_kernel(
    const float* __restrict__ w0, const float* __restrict__ w1,
    const float* __restrict__ w2, const float* __restrict__ w3,
    bf16* __restrict__ out)
{
    const int sel = blockIdx.y;
    const float* src = sel == 0 ? w0 : sel == 1 ? w1 : sel == 2 ? w2 : w3;
    const int i = (blockIdx.x * 256 + threadIdx.x) * 8;
    float4 a = *(const float4*)(src + i);
    float4 b = *(const float4*)(src + i + 4);
    uint4 u;
    u.x = pack2bf(a.x, a.y); u.y = pack2bf(a.z, a.w);
    u.z = pack2bf(b.x, b.y); u.w = pack2bf(b.z, b.w);
    *(uint4*)(void*)(out + (size_t)sel * 65536 + i) = u;
}

// ---- src/tgt (b,c,n) f32 -> (b,n,c) bf16 via LDS tile transpose.
__global__ __launch_bounds__(256) void txp_kernel(
    const float* __restrict__ src, const float* __restrict__ tgt,
    bf16* __restrict__ oS, bf16* __restrict__ oT)
{
    const int b = blockIdx.z & 7;
    const float* in = (blockIdx.z >> 3) ? tgt : src;
    bf16* out = (blockIdx.z >> 3) ? oT : oS;
    const int n0 = blockIdx.x * 64, c0 = blockIdx.y * 64;
    __shared__ float tile[64][65];
    const int t = threadIdx.x;
#pragma unroll
    for (int i = 0; i < 4; ++i) {
        int idx = t + i * 256;
        int cl = idx >> 4, n4 = (idx & 15) * 4;
        float4 v = *(const float4*)(in + ((size_t)b * DIM + c0 + cl) * NPIX + n0 + n4);
        tile[cl][n4] = v.x; tile[cl][n4 + 1] = v.y;
        tile[cl][n4 + 2] = v.z; tile[cl][n4 + 3] = v.w;
    }
    __syncthreads();
#pragma unroll
    for (int i = 0; i < 2; ++i) {
        int idx = t + i * 256;
        int nl = idx >> 3, c8 = (idx & 7) * 8;
        uint4 u;
        u.x = pack2bf(tile[c8 + 0][nl], tile[c8 + 1][nl]);
        u.y = pack2bf(tile[c8 + 2][nl], tile[c8 + 3][nl]);
        u.z = pack2bf(tile[c8 + 4][nl], tile[c8 + 5][nl]);
        u.w = pack2bf(tile[c8 + 6][nl], tile[c8 + 7][nl]);
        *(uint4*)(void*)(out + ((size_t)b * NPIX + n0 + nl) * DIM + c0 + c8) = u;
    }
}

// ---- 1x1 conv as MFMA GEMM with register double-buffered K-prefetch.
// D[n][m] = sum_c X[n][c] * W[m][c] + bias[m].
// X: (b,n,c) bf16; W: (m,c) bf16. Block: 64 n x 128 m, 4 waves (16 n each).
// MODE 0: f32 (b,c,n) -> Yf.
// MODE 1: bf16 *scale -> fragment-order QF/KF: [bh][kc][dk][lane][j].
// MODE 2: bf16 -> fragment-order VF: [bh][kc][kb][dt][lane][j].
template <int MODE>
__global__ __launch_bounds__(256) void conv_kernel(
    const bf16* __restrict__ X, const bf16* __restrict__ Wb,
    const float* __restrict__ bias, float scale,
    bf16* __restrict__ Yb, float* __restrict__ Yf)
{
    const int b  = blockIdx.z, mh = blockIdx.y;
    const int n0 = blockIdx.x * 64;
    const int w  = threadIdx.x >> 6, l = threadIdx.x & 63;
    const int lo = l & 15, hi = l >> 4;
    const int nrow = n0 + w * 16 + lo;

    const bf16* xp = X + ((size_t)b * NPIX + nrow) * DIM + hi * 8;
    const bf16* wp = Wb + ((size_t)(mh * 128 + lo)) * DIM + hi * 8;

    f32x4 acc[8];
#pragma unroll
    for (int mt = 0; mt < 8; ++mt) acc[mt] = (f32x4){0.f, 0.f, 0.f, 0.f};

    // preload k0 = 0 fragments
    bf16x8 a = *(const bf16x8*)(const void*)(xp);
    bf16x8 bfr[8];
#pragma unroll
    for (int mt = 0; mt < 8; ++mt)
        bfr[mt] = *(const bf16x8*)(const void*)(wp + (size_t)mt * 16 * DIM);

#pragma unroll
    for (int k0 = 0; k0 < DIM; k0 += 32) {
        bf16x8 a2, bfr2[8];
        const int kn = (k0 + 32) & (DIM - 1);   // wrap: last-iter loads are L1 hits
        a2 = *(const bf16x8*)(const void*)(xp + kn);
#pragma unroll
        for (int mt = 0; mt < 8; ++mt)
            bfr2[mt] = *(const bf16x8*)(const void*)(wp + (size_t)mt * 16 * DIM + kn);
#pragma unroll
        for (int mt = 0; mt < 8; ++mt)
            acc[mt] = __builtin_amdgcn_mfma_f32_16x16x32_bf16(a, bfr[mt], acc[mt], 0, 0, 0);
        a = a2;
#pragma unroll
        for (int mt = 0; mt < 8; ++mt) bfr[mt] = bfr2[mt];
    }

    const int nb = n0 + w * 16 + hi * 4;   // first of 4 consecutive n (rows r)
#pragma unroll
    for (int mt = 0; mt < 8; ++mt) {
        const int m = mh * 128 + mt * 16 + lo;
        const float bv = bias[m];
        if (MODE == 1) {
            const int h = m >> 6, d = m & 63;
            const size_t fb = (((size_t)(b * NHEADS + h) * KCN + (nb >> 5)) * 4 + (d >> 4)) * 512
                            + ((((d >> 3) & 1) * 32) + (nb & 31)) * 8 + (d & 7);
#pragma unroll
            for (int r = 0; r < 4; ++r)
                Yb[fb + r * 8] = __float2bfloat16((acc[mt][r] + bv) * scale);
        } else if (MODE == 2) {
            const int h = m >> 6, dv = m & 63;
            const size_t fb = ((((size_t)(b * NHEADS + h) * KCN + (nb >> 5)) * 2 + ((nb >> 4) & 1)) * 2
                               + (dv >> 5)) * 512
                            + ((((nb >> 3) & 1) * 32) + (dv & 31)) * 8 + (nb & 7);
            uint2 u = make_uint2(pack2bf(acc[mt][0] + bv, acc[mt][1] + bv),
                                 pack2bf(acc[mt][2] + bv, acc[mt][3] + bv));
            *(uint2*)(void*)(Yb + fb) = u;
        } else {
            float4 v = make_float4(acc[mt][0] + bv, acc[mt][1] + bv,
                                   acc[mt][2] + bv, acc[mt][3] + bv);
            *(float4*)(void*)(Yf + ((size_t)b * DIM + m) * NPIX + nb) = v;
        }
    }
}

// ---- MFMA flash attention, 32x32x16, no LDS, permlane-only cross-lane,
// UNROLL-2 PING-PONG register prefetch (no rotate movs -> no early waitcnt:
// each buffer's loads retire one full compute-phase after issue).
// Fragment-order operands: every load is base + lane*16B (8 lines/instr).
// QF/KF: [bh][kc][dk][64 lanes][8]; VF: [bh][kc][kb][dt][64 lanes][8].
// Op: (b,n,c) bf16. Block: 1 wave = 64 queries (2 sub-tiles). Grid (36,4,8).
__global__ __launch_bounds__(64) void attn_kernel(
    const bf16* __restrict__ Qt, const bf16* __restrict__ Kt,
    const bf16* __restrict__ Vt, bf16* __restrict__ Op)
{
    const int b = blockIdx.z, h = blockIdx.y;
    const int l = threadIdx.x & 63;
    const int ln = l & 31, h2 = l >> 5;
    const int nq = blockIdx.x * 64;
    const int bh = b * NHEADS + h;

    const bf16* QB = Qt + ((size_t)bh * KCN + blockIdx.x * 2) * 2048 + l * 8;
    const bf16* KB = Kt + (size_t)bh * KCN * 2048 + l * 8;
    const bf16* VB = Vt + (size_t)bh * KCN * 2048 + l * 8;

    // Q B-frags: lane holds Q[q=nq+qs*32+ln][dk*16+h2*8+j]
    bf16x8 qf[2][4];
#pragma unroll
    for (int qs = 0; qs < 2; ++qs)
#pragma unroll
        for (int dk = 0; dk < 4; ++dk)
            qf[qs][dk] = *(const bf16x8*)(const void*)(QB + qs * 2048 + dk * 512);

    f32x16 oacc[2][2];   // [qs][dt]: O^T[d = dt*32 + row][q]
#pragma unroll
    for (int qs = 0; qs < 2; ++qs)
#pragma unroll
        for (int dt = 0; dt < 2; ++dt)
#pragma unroll
            for (int r = 0; r < 16; ++r) oacc[qs][dt][r] = 0.f;
    float lsum[2] = {0.f, 0.f};

    bf16x8 kfA[4], kfB[4];
    bf16x8 vfA[2][2], vfB[2][2];

    auto load_chunk = [&](int kc_, bf16x8 (&kfD)[4], bf16x8 (&vfD)[2][2]) {
        const bf16* KBn = KB + (size_t)kc_ * 2048;
        const bf16* VBn = VB + (size_t)kc_ * 2048;
#pragma unroll
        for (int dk = 0; dk < 4; ++dk)
            kfD[dk] = *(const bf16x8*)(const void*)(KBn + dk * 512);
#pragma unroll
        for (int kb = 0; kb < 2; ++kb)
#pragma unroll
            for (int dt = 0; dt < 2; ++dt)
                vfD[kb][dt] = *(const bf16x8*)(const void*)(VBn + kb * 1024 + dt * 512);
    };

    auto compute = [&](const bf16x8 (&kfC)[4], const bf16x8 (&vfC)[2][2]) {
#pragma unroll
        for (int qs = 0; qs < 2; ++qs) {
            f32x16 s;
#pragma unroll
            for (int r = 0; r < 16; ++r) s[r] = 0.f;
#pragma unroll
            for (int dk = 0; dk < 4; ++dk)
                s = __builtin_amdgcn_mfma_f32_32x32x16_bf16(kfC[dk], qf[qs][dk], s, 0, 0, 0);

            // P = exp2(clamp(S)); word p covers keys 8*(p>>1)+4*h2+2*(p&1)+{0,1}
            float ls = 0.f;
            unsigned int pk[8];
#pragma unroll
            for (int p = 0; p < 8; ++p) {
                float ea = __builtin_amdgcn_exp2f(
                    __builtin_amdgcn_fmed3f(s[2 * p],     -CLAMP_L2E, CLAMP_L2E));
                float eb = __builtin_amdgcn_exp2f(
                    __builtin_amdgcn_fmed3f(s[2 * p + 1], -CLAMP_L2E, CLAMP_L2E));
                ls += ea + eb;
                pk[p] = pack2bf(ea, eb);
            }
            lsum[qs] += ls;

            // P^T B-frags via half-wave swaps:
            // after swap(a,b): a = {a.lo32 | b.lo32}, b = {a.hi32 | b.hi32}
            unsigned int c00 = pk[0], c02 = pk[2], c01 = pk[1], c03 = pk[3];
            unsigned int c10 = pk[4], c12 = pk[6], c11 = pk[5], c13 = pk[7];
            asm("v_permlane32_swap_b32 %0, %1" : "+v"(c00), "+v"(c02));
            asm("v_permlane32_swap_b32 %0, %1" : "+v"(c01), "+v"(c03));
            asm("v_permlane32_swap_b32 %0, %1" : "+v"(c10), "+v"(c12));
            asm("v_permlane32_swap_b32 %0, %1" : "+v"(c11), "+v"(c13));
            union { unsigned int u[4]; bf16x8 v; } pb0, pb1;
            pb0.u[0] = c00; pb0.u[1] = c01; pb0.u[2] = c02; pb0.u[3] = c03;
            pb1.u[0] = c10; pb1.u[1] = c11; pb1.u[2] = c12; pb1.u[3] = c13;

#pragma unroll
            for (int dt = 0; dt < 2; ++dt) {
                oacc[qs][dt] = __builtin_amdgcn_mfma_f32_32x32x16_bf16(vfC[0][dt], pb0.v, oacc[qs][dt], 0, 0, 0);
                oacc[qs][dt] = __builtin_amdgcn_mfma_f32_32x32x16_bf16(vfC[1][dt], pb1.v, oacc[qs][dt], 0, 0, 0);
            }
        }
    };

    load_chunk(0, kfA, vfA);
    for (int kc = 0; kc < KCN; kc += 2) {
        load_chunk(kc + 1, kfB, vfB);                    // fill B while computing A
        compute(kfA, vfA);
        load_chunk(kc + 2 == KCN ? 0 : kc + 2, kfA, vfA); // fill A while computing B
        compute(kfB, vfB);
    }

    // normalize: lane's 32 outputs all belong to query q = nq + qs*32 + ln
    float inv[2];
#pragma unroll
    for (int qs = 0; qs < 2; ++qs) {
        float t = lsum[qs] + __shfl_xor(lsum[qs], 32);
        inv[qs] = 1.f / t;
    }

    // store Op (b,n,c): n = nq + qs*32 + ln; c = h*64 + dt*32 + 8*g + 4*h2 + (0..3)
#pragma unroll
    for (int qs = 0; qs < 2; ++qs) {
        bf16* rowp = Op + ((size_t)b * NPIX + nq + qs * 32 + ln) * DIM + h * HDIM;
#pragma unroll
        for (int dt = 0; dt < 2; ++dt)
#pragma unroll
            for (int g = 0; g < 4; ++g) {
                float v0 = oacc[qs][dt][g * 4 + 0] * inv[qs];
                float v1 = oacc[qs][dt][g * 4 + 1] * inv[qs];
                float v2 = oacc[qs][dt][g * 4 + 2] * inv[qs];
                float v3 = oacc[qs][dt][g * 4 + 3] * inv[qs];
                uint2 u = make_uint2(pack2bf(v0, v1), pack2bf(v2, v3));
                *(uint2*)(void*)(rowp + dt * 32 + g * 8 + h2 * 4) = u;
            }
    }
}

extern "C" void kernel_launch(void* const* d_in, const int* in_sizes, int n_in,
                              void* d_out, int out_size, void* d_ws, size_t ws_size,
                              hipStream_t stream) {
    const float* src = (const float*)d_in[0];
    const float* tgt = (const float*)d_in[1];
    const float* qw  = (const float*)d_in[2];
    const float* qb  = (const float*)d_in[3];
    const float* kw  = (const float*)d_in[4];
    const float* kb  = (const float*)d_in[5];
    const float* vw  = (const float*)d_in[6];
    const float* vb  = (const float*)d_in[7];
    const float* ow  = (const float*)d_in[8];
    const float* ob  = (const float*)d_in[9];
    float* out = (float*)d_out;

    const size_t TEN = (size_t)NBATCH * DIM * NPIX;  // 4,718,592
    bf16* Wbf  = (bf16*)d_ws;          // 4 x 65536
    bf16* XbfS = Wbf  + 4 * 65536;     // (b,n,c)
    bf16* XbfT = XbfS + TEN;           // (b,n,c)
    bf16* Qt   = XbfT + TEN;           // fragment-order QF, prescaled
    bf16* Kt   = Qt   + TEN;           // fragment-order KF
    bf16* Vt   = Kt   + TEN;           // fragment-order VF
    bf16* Op   = Vt   + TEN;           // (b,n,c)

    cvt_w_kernel<<<dim3(32, 4, 1), 256, 0, stream>>>(qw, kw, vw, ow, Wbf);
    txp_kernel<<<dim3(NPIX / 64, DIM / 64, 2 * NBATCH), 256, 0, stream>>>(src, tgt, XbfS, XbfT);

    dim3 cgrid(NPIX / 64, 2, NBATCH);
    conv_kernel<1><<<cgrid, 256, 0, stream>>>(XbfS, Wbf,             qb, SCALE_L2E, Qt, nullptr);
    conv_kernel<1><<<cgrid, 256, 0, stream>>>(XbfT, Wbf + 1 * 65536, kb, 1.0f,      Kt, nullptr);
    conv_kernel<2><<<cgrid, 256, 0, stream>>>(XbfT, Wbf + 2 * 65536, vb, 1.0f,      Vt, nullptr);

    attn_kernel<<<dim3(NPIX / 64, NHEADS, NBATCH), 64, 0, stream>>>(Qt, Kt, Vt, Op);

    conv_kernel<0><<<cgrid, 256, 0, stream>>>(Op, Wbf + 3 * 65536, ob, 1.0f, nullptr, out);
}